// Round 2
// baseline (7975.035 us; speedup 1.0000x reference)
//
#include <hip/hip_runtime.h>
#include <stdint.h>

// ---------------------------------------------------------------------------
// LSTM_14242111554073  (B=32, S=512, IN=512, H=1024, fp32 in/out)
// Phase 1: gx = x @ [wxf|wxi|wxo|wxc]  (bf16 MFMA GEMM, 16384x512x4096)
// Phase 2: persistent scan.
//   R2 change: 64 WGs x 512 threads (was 128 x 256). Each WG owns 16 h-cols
//   (64 gate cols). Halves the per-step all-to-all broadcast: 64 consumers
//   re-reading the hot 64KB h-slot instead of 128 (hot-line LLC request count
//   halved), producers-per-chunk 4 -> 2, per-wave sweep 16 -> 8 loads.
//   Wh slice (128KB) forces single-copy K-reduce: glds[32][68] f32 accumulated
//   via LDS atomicAdd (ds_add_f32), 4-way K-split x 2 row-tiles across the 8
//   waves (no redundant h loads). Epilogue threads read 4 floats and re-zero
//   their own slots (race-free). Flag-free sentinel sync as R1.
// ---------------------------------------------------------------------------

typedef short bf16x8 __attribute__((ext_vector_type(8)));
typedef float f32x4  __attribute__((ext_vector_type(4)));
typedef unsigned int uint4v __attribute__((ext_vector_type(4)));

#define MFMA16(a, b, c) __builtin_amdgcn_mfma_f32_16x16x32_bf16((a), (b), (c), 0, 0, 0)

__device__ __forceinline__ unsigned short f2bf(float f) {
    unsigned int u = __builtin_bit_cast(unsigned int, f);
    u = (u + 0x7FFFu + ((u >> 16) & 1u)) >> 16;   // RNE
    return (unsigned short)u;
}
__device__ __forceinline__ float bf2f(unsigned short h) {
    unsigned int u = ((unsigned int)h) << 16;
    return __builtin_bit_cast(float, u);
}
__device__ __forceinline__ float sigmoidf_(float x) { return 1.0f / (1.0f + __expf(-x)); }
__device__ __forceinline__ float tanhf_(float x)    { return 1.0f - 2.0f / (__expf(2.0f * x) + 1.0f); }

// ---------------------------------------------------------------------------
// Kernel 1: gx GEMM.  C[16384 x 4096] = X[16384 x 512] @ Wx[512 x 4096], bf16 out.
// (unchanged — scan dominates)
// ---------------------------------------------------------------------------
__global__ void __launch_bounds__(256) gx_gemm(
    const float* __restrict__ X,
    const float* __restrict__ Wf, const float* __restrict__ Wi,
    const float* __restrict__ Wo, const float* __restrict__ Wc,
    unsigned short* __restrict__ gxOut)
{
    __shared__ unsigned short As[128 * 40];
    __shared__ unsigned short Bs[128 * 40];

    const int tid  = threadIdx.x;
    const int lane = tid & 63;
    const int wid  = tid >> 6;
    const int lr   = lane & 15;
    const int lq   = lane >> 4;

    const int m0 = blockIdx.x * 128;
    const int n0 = blockIdx.y * 128;
    const float* Wg = (n0 < 1024) ? Wf : (n0 < 2048) ? Wi : (n0 < 3072) ? Wo : Wc;
    const int ncol0 = n0 & 1023;

    const int mw = (wid & 1) * 64;
    const int nw = (wid >> 1) * 64;

    f32x4 acc[4][4];
#pragma unroll
    for (int i = 0; i < 4; i++)
#pragma unroll
        for (int j = 0; j < 4; j++) acc[i][j] = (f32x4){0.f, 0.f, 0.f, 0.f};

    for (int k0 = 0; k0 < 512; k0 += 32) {
#pragma unroll
        for (int i = 0; i < 4; i++) {
            int s   = tid + i * 256;
            int row = s >> 3;
            int c4  = s & 7;
            float4 v = *(const float4*)(X + (size_t)(m0 + row) * 512 + k0 + c4 * 4);
            ushort4 h;
            h.x = f2bf(v.x); h.y = f2bf(v.y); h.z = f2bf(v.z); h.w = f2bf(v.w);
            *(ushort4*)(As + row * 40 + c4 * 4) = h;
        }
#pragma unroll
        for (int i = 0; i < 4; i++) {
            int s  = tid + i * 256;
            int kk = s >> 5;
            int c4 = s & 31;
            float4 v = *(const float4*)(Wg + (size_t)(k0 + kk) * 1024 + ncol0 + c4 * 4);
            Bs[(c4 * 4 + 0) * 40 + kk] = f2bf(v.x);
            Bs[(c4 * 4 + 1) * 40 + kk] = f2bf(v.y);
            Bs[(c4 * 4 + 2) * 40 + kk] = f2bf(v.z);
            Bs[(c4 * 4 + 3) * 40 + kk] = f2bf(v.w);
        }
        __syncthreads();

        bf16x8 af[4], bfr[4];
#pragma unroll
        for (int tm = 0; tm < 4; tm++)
            af[tm] = *(const bf16x8*)(As + (mw + tm * 16 + lr) * 40 + lq * 8);
#pragma unroll
        for (int tn = 0; tn < 4; tn++)
            bfr[tn] = *(const bf16x8*)(Bs + (nw + tn * 16 + lr) * 40 + lq * 8);
#pragma unroll
        for (int tm = 0; tm < 4; tm++)
#pragma unroll
            for (int tn = 0; tn < 4; tn++)
                acc[tm][tn] = MFMA16(af[tm], bfr[tn], acc[tm][tn]);
        __syncthreads();
    }

#pragma unroll
    for (int tm = 0; tm < 4; tm++)
#pragma unroll
        for (int tn = 0; tn < 4; tn++)
#pragma unroll
            for (int r = 0; r < 4; r++) {
                int row = m0 + mw + tm * 16 + lq * 4 + r;
                int col = n0 + nw + tn * 16 + lr;
                gxOut[(size_t)row * 4096 + col] = f2bf(acc[tm][tn][r]);
            }
}

// ---------------------------------------------------------------------------
// Kernel 2: persistent scan. 64 WGs x 512 threads (8 waves). WG w owns h-cols
// j0=w*16..j0+15 (64 gate cols: c = g*16 + jj). LDS (dynamic):
//   Wlds  [64 cols][1032 k] bf16 (col stride 1032 ush = 2064 B) : 132096 B
//   glds  [32 b][68] f32 single-copy accumulator (ds_add_f32)   :   8704 B
//   blds  [64] f32                                              :    256 B
// total 141056 B -> 1 WG/CU (64 WGs on 256 CUs: co-residency guaranteed)
// Wave wid: kh2 = wid&3 (K quarter, 256), rt = wid>>2 (row tile of 16).
// Per wave: 8 chunks of 32k, 1 dwordx4/lane/chunk, 4 MFMA/chunk (col tiles).
// ---------------------------------------------------------------------------
#define NWG 64
#define LDS2_BYTES 141056

__global__ void __launch_bounds__(512, 2) lstm_scan(
    const float* __restrict__ Whf, const float* __restrict__ Whi,
    const float* __restrict__ Who, const float* __restrict__ Whc,
    const float* __restrict__ Bf,  const float* __restrict__ Bi,
    const float* __restrict__ Bo,  const float* __restrict__ Bc,
    const unsigned short* __restrict__ gx,
    unsigned short* __restrict__ hhist,   // [512][32][1024] bf16, slot t = h_t
                                          // pre-filled 0xFF (sentinel)
    float* __restrict__ out)
{
    extern __shared__ char lds[];
    unsigned short* Wlds = (unsigned short*)lds;            // 132096 B
    float* glds = (float*)(lds + 132096);                   //   8704 B: [32][68]
    float* blds = (float*)(lds + 140800);                   //    256 B

    const int tid  = threadIdx.x;
    const int w    = blockIdx.x;
    const int j0   = w * 16;
    const int lane = tid & 63;
    const int wid  = tid >> 6;
    const int kh2  = wid & 3;           // K quarter: k in [kh2*256, +256)
    const int rt   = wid >> 2;          // row tile: rows [rt*16, +16)
    const int lr   = lane & 15;
    const int lq   = lane >> 4;

    // ---- biases ----
    if (tid < 64) {
        int g = tid >> 4, jj = tid & 15;
        const float* bp = (g == 0) ? Bf : (g == 1) ? Bi : (g == 2) ? Bo : Bc;
        blds[tid] = bp[j0 + jj];
    }
    // ---- zero glds accumulator ----
    for (int i = tid; i < 32 * 68; i += 512) glds[i] = 0.f;
    // ---- Wh slice -> LDS bf16 col-major [col][k] ----
#pragma unroll 4
    for (int i = 0; i < 128; i++) {
        int e = i * 512 + tid;          // 0..65535
        int k = e >> 6;
        int c = e & 63;
        int g = c >> 4, jj = c & 15;
        const float* wp = (g == 0) ? Whf : (g == 1) ? Whi : (g == 2) ? Who : Whc;
        Wlds[c * 1032 + k] = f2bf(wp[(size_t)k * 1024 + j0 + jj]);
    }

    const int cb = tid >> 4;            // epilogue batch row (0..31)
    const int cj = tid & 15;            // epilogue h-col within slice (0..15)
    float c_reg = 0.f;

    __syncthreads();

    for (int t = 0; t < 512; t++) {
        // ---- prefetch gx for this step (overlaps the sentinel sweep) ----
        const unsigned short* gxr = gx + ((size_t)(cb * 512 + t)) * 4096 + j0 + cj;
        float gxv[4];
#pragma unroll
        for (int g = 0; g < 4; g++) gxv[g] = bf2f(gxr[(size_t)g * 1024]);

        if (t > 0) {
            // ---- sentinel-sweep GEMM: wave (kh2, rt) covers rows [rt*16,+16)
            //      x K [kh2*256,+256) in 8 chunks of 32k; 4 col-tiles each ----
            const unsigned short* hsrc = hhist + (size_t)t * 32768;

            f32x4 acc[4];
#pragma unroll
            for (int ct = 0; ct < 4; ct++) acc[ct] = (f32x4){0.f, 0.f, 0.f, 0.f};

            uint4v fa[8];
            unsigned int pend = 0xFFu;
            while (pend) {
#pragma unroll
                for (int kk = 0; kk < 8; kk++) {
                    if (pend & (1u << kk)) {
                        int kke = (kk + w) & 7;          // stagger per WG
                        int kb  = kh2 * 256 + kke * 32;
                        const unsigned short* p = hsrc + (rt * 16 + lr) * 1024
                                                   + kb + lq * 8;
                        asm volatile("global_load_dwordx4 %0, %1, off sc0 sc1"
                                     : "=v"(fa[kk]) : "v"(p));
                    }
                }
                asm volatile("s_waitcnt vmcnt(0)" ::: "memory");
                __builtin_amdgcn_sched_barrier(0);

                unsigned int np = 0;
#pragma unroll
                for (int kk = 0; kk < 8; kk++) {
                    if (pend & (1u << kk)) {
                        uint4v u = fa[kk];
                        bool dirty = (u[0] == 0xFFFFFFFFu) | (u[1] == 0xFFFFFFFFu)
                                   | (u[2] == 0xFFFFFFFFu) | (u[3] == 0xFFFFFFFFu);
                        if (__any(dirty)) {
                            np |= 1u << kk;
                        } else {
                            int kke = (kk + w) & 7;
                            int kb  = kh2 * 256 + kke * 32;
                            bf16x8 a = __builtin_bit_cast(bf16x8, u);
#pragma unroll
                            for (int ct = 0; ct < 4; ct++) {
                                bf16x8 b = *(const bf16x8*)(Wlds
                                           + (ct * 16 + lr) * 1032 + kb + lq * 8);
                                acc[ct] = MFMA16(a, b, acc[ct]);
                            }
                        }
                    }
                }
                pend = np;
            }

            // ---- K-reduce: ds_add_f32 into single-copy glds[32][68] ----
            // C/D layout: row = lq*4+r (batch within tile), col = lr
#pragma unroll
            for (int ct = 0; ct < 4; ct++)
#pragma unroll
                for (int r = 0; r < 4; r++)
                    atomicAdd(&glds[(rt * 16 + lq * 4 + r) * 68 + ct * 16 + lr],
                              acc[ct][r]);
        }
        __syncthreads();   // barrier B: all partial adds visible

        // ---- pointwise epilogue: thread (cb, cj) ----
        float sg[4];
#pragma unroll
        for (int g = 0; g < 4; g++) {
            float dot = (t > 0) ? glds[cb * 68 + g * 16 + cj] : 0.f;
            sg[g] = sigmoidf_(dot + gxv[g] + blds[g * 16 + cj]);
        }
        // re-zero own accumulator slots (only this thread reads them)
#pragma unroll
        for (int g = 0; g < 4; g++) glds[cb * 68 + g * 16 + cj] = 0.f;

        float cn = sg[0] * c_reg + sg[1] * sg[3];   // f*c + i*sigmoid(cand)
        c_reg = cn;
        float hn = sg[2] * tanhf_(cn);

        if (t < 511) {
            // ---- h_{t+1}: gather 16 cols of row cb into two sc1 dwordx4 ----
            unsigned int hb = (unsigned int)f2bf(hn);
            unsigned int nb = (unsigned int)__shfl_xor((int)hb, 1);
            unsigned int v  = (hb & 0xFFFFu) | (nb << 16);     // cols (cj, cj+1), even cj
            unsigned int v2 = (unsigned int)__shfl_xor((int)v, 2);
            unsigned int v4 = (unsigned int)__shfl_xor((int)v, 4);
            unsigned int v6 = (unsigned int)__shfl_xor((int)v2, 4);
            if ((cj & 7) == 0) {                               // cj == 0 or 8
                uint4v q;
                q[0] = v; q[1] = v2; q[2] = v4; q[3] = v6;     // 8 cols from cj
                unsigned short* dst = hhist + (size_t)(t + 1) * 32768
                                      + cb * 1024 + j0 + cj;
                asm volatile("global_store_dwordx4 %0, %1, off sc1"
                             :: "v"(dst), "v"(q) : "memory");
            }
            out[((size_t)cb * 512 + t) * 1024 + j0 + cj] = sg[2];   // seq out = o gate
        } else {
            out[((size_t)cb * 512 + t) * 1024 + j0 + cj] = sg[2];
            out[16777216 + cb * 1024 + j0 + cj]          = hn;   // ht
            out[16777216 + 32768 + cb * 1024 + j0 + cj]  = cn;   // ct
        }
        __syncthreads();   // barrier D: glds re-zeroed before next step's adds
    }
}

__global__ void ws_diag(float* out, float mb) { out[threadIdx.x] = -mb; }

extern "C" void kernel_launch(void* const* d_in, const int* in_sizes, int n_in,
                              void* d_out, int out_size, void* d_ws, size_t ws_size,
                              hipStream_t stream)
{
    const float* x   = (const float*)d_in[0];
    const float* wxf = (const float*)d_in[1];
    const float* whf = (const float*)d_in[2];
    const float* bhf = (const float*)d_in[3];
    const float* wxi = (const float*)d_in[4];
    const float* whi = (const float*)d_in[5];
    const float* bhi = (const float*)d_in[6];
    const float* wxo = (const float*)d_in[7];
    const float* who = (const float*)d_in[8];
    const float* bho = (const float*)d_in[9];
    const float* wxc = (const float*)d_in[10];
    const float* whc = (const float*)d_in[11];
    const float* bhc = (const float*)d_in[12];
    float* out = (float*)d_out;

    const size_t GX_BYTES = (size_t)16384 * 4096 * 2;    // 134217728
    const size_t HH_BYTES = (size_t)512 * 32 * 1024 * 2; //  33554432
    const size_t NEED = GX_BYTES + HH_BYTES;

    if (ws_size < NEED) {
        ws_diag<<<dim3(1), dim3(256), 0, stream>>>(out, (float)(ws_size >> 20));
        return;
    }

    unsigned short* gxbuf = (unsigned short*)d_ws;
    unsigned short* hh    = (unsigned short*)((char*)d_ws + GX_BYTES);

    (void)hipFuncSetAttribute((const void*)lstm_scan,
                              hipFuncAttributeMaxDynamicSharedMemorySize, LDS2_BYTES);

    gx_gemm<<<dim3(128, 32), dim3(256), 0, stream>>>(x, wxf, wxi, wxo, wxc, gxbuf);
    // sentinel-fill hhist: bf16 0xFFFF (-NaN) is unreachable for real h (|h|<1)
    hipMemsetAsync(hh, 0xFF, HH_BYTES, stream);
    lstm_scan<<<dim3(NWG), dim3(512), LDS2_BYTES, stream>>>(
        whf, whi, who, whc, bhf, bhi, bho, bhc, gxbuf, hh, out);
}

// Round 3
// 2985.645 us; speedup vs baseline: 2.6711x; 2.6711x over previous
//
#include <hip/hip_runtime.h>
#include <stdint.h>

// ---------------------------------------------------------------------------
// LSTM_14242111554073  (B=32, S=512, IN=512, H=1024, fp32 in/out)
// Phase 1: gx = x @ [wxf|wxi|wxo|wxc]  (bf16 MFMA GEMM, 16384x512x4096)
// Phase 2: persistent scan, 128 WGs x 256 thr (R1 topology, proven 2578us).
//   R3 changes (R2's LDS f32 atomicAdd = CAS-loop regression reverted):
//   1) Wh B-fragments hoisted to REGISTERS (64 VGPR/wave, constant over t);
//      Wlds (66KB) deleted -> shorter notice->MFMA tail, no init conflicts.
//   2) K-reduce partials re-laid col-major [kq][col][row], col stride 40:
//      ds_write_b128 perfectly tiled, epilogue reads 2-way (conflict-free).
//   3) glds double-buffered by t parity -> barrier D dropped (1 barrier/step).
//   Flag-free sentinel sync as R1 (hhist prefilled 0xFF = bf16 -NaN).
// ---------------------------------------------------------------------------

typedef short bf16x8 __attribute__((ext_vector_type(8)));
typedef float f32x4  __attribute__((ext_vector_type(4)));
typedef unsigned int uint4v __attribute__((ext_vector_type(4)));

#define MFMA16(a, b, c) __builtin_amdgcn_mfma_f32_16x16x32_bf16((a), (b), (c), 0, 0, 0)

__device__ __forceinline__ unsigned short f2bf(float f) {
    unsigned int u = __builtin_bit_cast(unsigned int, f);
    u = (u + 0x7FFFu + ((u >> 16) & 1u)) >> 16;   // RNE
    return (unsigned short)u;
}
__device__ __forceinline__ float bf2f(unsigned short h) {
    unsigned int u = ((unsigned int)h) << 16;
    return __builtin_bit_cast(float, u);
}
__device__ __forceinline__ float sigmoidf_(float x) { return 1.0f / (1.0f + __expf(-x)); }
__device__ __forceinline__ float tanhf_(float x)    { return 1.0f - 2.0f / (__expf(2.0f * x) + 1.0f); }

// ---------------------------------------------------------------------------
// Kernel 1: gx GEMM.  C[16384 x 4096] = X[16384 x 512] @ Wx[512 x 4096], bf16 out.
// (unchanged — scan dominates)
// ---------------------------------------------------------------------------
__global__ void __launch_bounds__(256) gx_gemm(
    const float* __restrict__ X,
    const float* __restrict__ Wf, const float* __restrict__ Wi,
    const float* __restrict__ Wo, const float* __restrict__ Wc,
    unsigned short* __restrict__ gxOut)
{
    __shared__ unsigned short As[128 * 40];
    __shared__ unsigned short Bs[128 * 40];

    const int tid  = threadIdx.x;
    const int lane = tid & 63;
    const int wid  = tid >> 6;
    const int lr   = lane & 15;
    const int lq   = lane >> 4;

    const int m0 = blockIdx.x * 128;
    const int n0 = blockIdx.y * 128;
    const float* Wg = (n0 < 1024) ? Wf : (n0 < 2048) ? Wi : (n0 < 3072) ? Wo : Wc;
    const int ncol0 = n0 & 1023;

    const int mw = (wid & 1) * 64;
    const int nw = (wid >> 1) * 64;

    f32x4 acc[4][4];
#pragma unroll
    for (int i = 0; i < 4; i++)
#pragma unroll
        for (int j = 0; j < 4; j++) acc[i][j] = (f32x4){0.f, 0.f, 0.f, 0.f};

    for (int k0 = 0; k0 < 512; k0 += 32) {
#pragma unroll
        for (int i = 0; i < 4; i++) {
            int s   = tid + i * 256;
            int row = s >> 3;
            int c4  = s & 7;
            float4 v = *(const float4*)(X + (size_t)(m0 + row) * 512 + k0 + c4 * 4);
            ushort4 h;
            h.x = f2bf(v.x); h.y = f2bf(v.y); h.z = f2bf(v.z); h.w = f2bf(v.w);
            *(ushort4*)(As + row * 40 + c4 * 4) = h;
        }
#pragma unroll
        for (int i = 0; i < 4; i++) {
            int s  = tid + i * 256;
            int kk = s >> 5;
            int c4 = s & 31;
            float4 v = *(const float4*)(Wg + (size_t)(k0 + kk) * 1024 + ncol0 + c4 * 4);
            Bs[(c4 * 4 + 0) * 40 + kk] = f2bf(v.x);
            Bs[(c4 * 4 + 1) * 40 + kk] = f2bf(v.y);
            Bs[(c4 * 4 + 2) * 40 + kk] = f2bf(v.z);
            Bs[(c4 * 4 + 3) * 40 + kk] = f2bf(v.w);
        }
        __syncthreads();

        bf16x8 af[4], bfr[4];
#pragma unroll
        for (int tm = 0; tm < 4; tm++)
            af[tm] = *(const bf16x8*)(As + (mw + tm * 16 + lr) * 40 + lq * 8);
#pragma unroll
        for (int tn = 0; tn < 4; tn++)
            bfr[tn] = *(const bf16x8*)(Bs + (nw + tn * 16 + lr) * 40 + lq * 8);
#pragma unroll
        for (int tm = 0; tm < 4; tm++)
#pragma unroll
            for (int tn = 0; tn < 4; tn++)
                acc[tm][tn] = MFMA16(af[tm], bfr[tn], acc[tm][tn]);
        __syncthreads();
    }

#pragma unroll
    for (int tm = 0; tm < 4; tm++)
#pragma unroll
        for (int tn = 0; tn < 4; tn++)
#pragma unroll
            for (int r = 0; r < 4; r++) {
                int row = m0 + mw + tm * 16 + lq * 4 + r;
                int col = n0 + nw + tn * 16 + lr;
                gxOut[(size_t)row * 4096 + col] = f2bf(acc[tm][tn][r]);
            }
}

// ---------------------------------------------------------------------------
// Kernel 2: persistent scan. 128 WGs x 256 threads. WG w owns h-cols
// j0=w*8..j0+7 (32 gate cols, arranged c = g*8+jj). LDS (dynamic):
//   glds  [2 buf][4 kq][32 col][40 row] f32 partials            : 40960 B
//   blds  [32] f32                                              :   128 B
// total 41088 B. Wh fragments live in registers (bfrag[2][8], 64 VGPR).
// Wave kq covers K [kq*256,+256) in 8 chunks of 32k; rows 0..31 (2 tiles).
// ---------------------------------------------------------------------------
#define NWG 128
#define LDS2_BYTES 41088
#define GBUF 5120     // floats per glds buffer (4 * 32 * 40)
#define KSTR 1280     // floats per kq slice (32 * 40)
#define CSTR 40       // floats per col

__global__ void __launch_bounds__(256, 1) lstm_scan(
    const float* __restrict__ Whf, const float* __restrict__ Whi,
    const float* __restrict__ Who, const float* __restrict__ Whc,
    const float* __restrict__ Bf,  const float* __restrict__ Bi,
    const float* __restrict__ Bo,  const float* __restrict__ Bc,
    const unsigned short* __restrict__ gx,
    unsigned short* __restrict__ hhist,   // [512][32][1024] bf16, slot t = h_t
                                          // pre-filled 0xFF (sentinel)
    float* __restrict__ out)
{
    extern __shared__ char lds[];
    float* glds = (float*)lds;            // 40960 B
    float* blds = (float*)(lds + 40960);  //   128 B

    const int tid  = threadIdx.x;
    const int w    = blockIdx.x;
    const int j0   = w * 8;
    const int lane = tid & 63;
    const int kq   = tid >> 6;          // wave id == K-split chunk
    const int lr   = lane & 15;
    const int lq   = lane >> 4;

    // ---- biases ----
    if (tid < 32) {
        int g = tid >> 3, jj = tid & 7;
        const float* bp = (g == 0) ? Bf : (g == 1) ? Bi : (g == 2) ? Bo : Bc;
        blds[tid] = bp[j0 + jj];
    }

    // ---- Wh B-fragments -> REGISTERS (constant over all t) ----
    // bfrag[tn][ks][j] = W_g[(kq*256 + ks*32 + lq*8 + j)][j0 + jj],
    // gate col = tn*16+lr -> g = col>>3, jj = col&7  (matches gx layout)
    bf16x8 bfrag[2][8];
#pragma unroll
    for (int tn = 0; tn < 2; tn++) {
        int col = tn * 16 + lr;
        int g = col >> 3, jj = col & 7;
        const float* wp = (g == 0) ? Whf : (g == 1) ? Whi : (g == 2) ? Who : Whc;
#pragma unroll
        for (int ks = 0; ks < 8; ks++) {
            int kbase = kq * 256 + ks * 32 + lq * 8;
            bf16x8 b;
#pragma unroll
            for (int j = 0; j < 8; j++)
                b[j] = (short)f2bf(wp[(size_t)(kbase + j) * 1024 + j0 + jj]);
            bfrag[tn][ks] = b;
        }
    }

    const int cb = tid >> 3;            // epilogue batch row
    const int cj = tid & 7;             // epilogue h-col within slice
    float c_reg = 0.f;

    __syncthreads();

    for (int t = 0; t < 512; t++) {
        float* gb = glds + (t & 1) * GBUF;

        // ---- prefetch gx for this step (overlaps the sentinel sweep) ----
        const unsigned short* gxr = gx + ((size_t)(cb * 512 + t)) * 4096 + j0 + cj;
        float gxv[4];
#pragma unroll
        for (int g = 0; g < 4; g++) gxv[g] = bf2f(gxr[(size_t)g * 1024]);

        if (t > 0) {
            // ---- sentinel-sweep GEMM: load h_t fragments via sc0+sc1 bypass,
            //      retry per 32-k chunk, fire MFMAs as chunks become ready ----
            const unsigned short* hsrc = hhist + (size_t)t * 32768;

            f32x4 acc[2][2];
#pragma unroll
            for (int a = 0; a < 2; a++)
#pragma unroll
                for (int b = 0; b < 2; b++) acc[a][b] = (f32x4){0.f, 0.f, 0.f, 0.f};

            uint4v f0[8], f1[8];
            unsigned int pend = 0xFFu;
            while (pend) {
#pragma unroll
                for (int ks = 0; ks < 8; ks++) {
                    if (pend & (1u << ks)) {
                        const unsigned short* p0 = hsrc + (lr) * 1024
                                                   + kq * 256 + ks * 32 + lq * 8;
                        const unsigned short* p1 = hsrc + (16 + lr) * 1024
                                                   + kq * 256 + ks * 32 + lq * 8;
                        asm volatile("global_load_dwordx4 %0, %1, off sc0 sc1"
                                     : "=v"(f0[ks]) : "v"(p0));
                        asm volatile("global_load_dwordx4 %0, %1, off sc0 sc1"
                                     : "=v"(f1[ks]) : "v"(p1));
                    }
                }
                asm volatile("s_waitcnt vmcnt(0)" ::: "memory");
                __builtin_amdgcn_sched_barrier(0);

                unsigned int np = 0;
#pragma unroll
                for (int ks = 0; ks < 8; ks++) {
                    if (pend & (1u << ks)) {
                        uint4v u0 = f0[ks], u1 = f1[ks];
                        bool dirty = (u0[0] == 0xFFFFFFFFu) | (u0[1] == 0xFFFFFFFFu)
                                   | (u0[2] == 0xFFFFFFFFu) | (u0[3] == 0xFFFFFFFFu)
                                   | (u1[0] == 0xFFFFFFFFu) | (u1[1] == 0xFFFFFFFFu)
                                   | (u1[2] == 0xFFFFFFFFu) | (u1[3] == 0xFFFFFFFFu);
                        if (__any(dirty)) {
                            np |= 1u << ks;
                        } else {
                            bf16x8 a0 = __builtin_bit_cast(bf16x8, f0[ks]);
                            bf16x8 a1 = __builtin_bit_cast(bf16x8, f1[ks]);
                            acc[0][0] = MFMA16(a0, bfrag[0][ks], acc[0][0]);
                            acc[0][1] = MFMA16(a0, bfrag[1][ks], acc[0][1]);
                            acc[1][0] = MFMA16(a1, bfrag[0][ks], acc[1][0]);
                            acc[1][1] = MFMA16(a1, bfrag[1][ks], acc[1][1]);
                        }
                    }
                }
                pend = np;
            }

            // ---- partials -> glds[t&1][kq][col][row], b128 rows lq*4..+3 ----
            // C/D layout: row-in-tile = lq*4+r, col = tn*16+lr
#pragma unroll
            for (int tm = 0; tm < 2; tm++)
#pragma unroll
                for (int tn = 0; tn < 2; tn++)
                    *(f32x4*)(gb + kq * KSTR + (tn * 16 + lr) * CSTR
                              + tm * 16 + lq * 4) = acc[tm][tn];
        }
        __syncthreads();   // barrier B: partials visible (the only barrier)

        // ---- pointwise epilogue: thread (cb, cj) ----
        float sg[4];
#pragma unroll
        for (int g = 0; g < 4; g++) {
            float dot = 0.f;
            if (t > 0) {
#pragma unroll
                for (int p = 0; p < 4; p++)
                    dot += gb[p * KSTR + (g * 8 + cj) * CSTR + cb];
            }
            sg[g] = sigmoidf_(dot + gxv[g] + blds[g * 8 + cj]);
        }
        float cn = sg[0] * c_reg + sg[1] * sg[3];   // f*c + i*sigmoid(cand)
        c_reg = cn;
        float hn = sg[2] * tanhf_(cn);

        if (t < 511) {
            // ---- h_{t+1}: gather 8 cols of row cb into one sc1 dwordx4 ----
            unsigned int hb = (unsigned int)f2bf(hn);
            unsigned int nb = (unsigned int)__shfl_xor((int)hb, 1);
            unsigned int v  = (hb & 0xFFFFu) | (nb << 16);     // cols (cj, cj+1), even cj
            unsigned int v2 = (unsigned int)__shfl_xor((int)v, 2);
            unsigned int v4 = (unsigned int)__shfl_xor((int)v, 4);
            unsigned int v6 = (unsigned int)__shfl_xor((int)v2, 4);
            if (cj == 0) {
                uint4v q;
                q[0] = v; q[1] = v2; q[2] = v4; q[3] = v6;     // cols 0..7
                unsigned short* dst = hhist + (size_t)(t + 1) * 32768
                                      + cb * 1024 + j0;
                asm volatile("global_store_dwordx4 %0, %1, off sc1"
                             :: "v"(dst), "v"(q) : "memory");
            }
            out[((size_t)cb * 512 + t) * 1024 + j0 + cj] = sg[2];   // seq out = o gate
        } else {
            out[((size_t)cb * 512 + t) * 1024 + j0 + cj] = sg[2];
            out[16777216 + cb * 1024 + j0 + cj]          = hn;   // ht
            out[16777216 + 32768 + cb * 1024 + j0 + cj]  = cn;   // ct
        }
        // no barrier D: glds is double-buffered by t parity; cross-step reuse
        // is separated by barrier B + the global h-store data dependency.
    }
}

__global__ void ws_diag(float* out, float mb) { out[threadIdx.x] = -mb; }

extern "C" void kernel_launch(void* const* d_in, const int* in_sizes, int n_in,
                              void* d_out, int out_size, void* d_ws, size_t ws_size,
                              hipStream_t stream)
{
    const float* x   = (const float*)d_in[0];
    const float* wxf = (const float*)d_in[1];
    const float* whf = (const float*)d_in[2];
    const float* bhf = (const float*)d_in[3];
    const float* wxi = (const float*)d_in[4];
    const float* whi = (const float*)d_in[5];
    const float* bhi = (const float*)d_in[6];
    const float* wxo = (const float*)d_in[7];
    const float* who = (const float*)d_in[8];
    const float* bho = (const float*)d_in[9];
    const float* wxc = (const float*)d_in[10];
    const float* whc = (const float*)d_in[11];
    const float* bhc = (const float*)d_in[12];
    float* out = (float*)d_out;

    const size_t GX_BYTES = (size_t)16384 * 4096 * 2;    // 134217728
    const size_t HH_BYTES = (size_t)512 * 32 * 1024 * 2; //  33554432
    const size_t NEED = GX_BYTES + HH_BYTES;

    if (ws_size < NEED) {
        ws_diag<<<dim3(1), dim3(256), 0, stream>>>(out, (float)(ws_size >> 20));
        return;
    }

    unsigned short* gxbuf = (unsigned short*)d_ws;
    unsigned short* hh    = (unsigned short*)((char*)d_ws + GX_BYTES);

    (void)hipFuncSetAttribute((const void*)lstm_scan,
                              hipFuncAttributeMaxDynamicSharedMemorySize, LDS2_BYTES);

    gx_gemm<<<dim3(128, 32), dim3(256), 0, stream>>>(x, wxf, wxi, wxo, wxc, gxbuf);
    // sentinel-fill hhist: bf16 0xFFFF (-NaN) is unreachable for real h (|h|<1)
    hipMemsetAsync(hh, 0xFF, HH_BYTES, stream);
    lstm_scan<<<dim3(NWG), dim3(256), LDS2_BYTES, stream>>>(
        whf, whi, who, whc, bhf, bhi, bho, bhc, gxbuf, hh, out);
}

// Round 4
// 2627.216 us; speedup vs baseline: 3.0355x; 1.1364x over previous
//
#include <hip/hip_runtime.h>
#include <stdint.h>

// ---------------------------------------------------------------------------
// LSTM_14242111554073  (B=32, S=512, IN=512, H=1024, fp32 in/out)
// Phase 1: gx = x @ [wxf|wxi|wxo|wxc]  (bf16 MFMA GEMM, 16384x512x4096)
// Phase 2: persistent scan.
//   R4 change: batch-split. LSTM rows are independent: h_{t+1}[b,:] depends
//   only on h_t[b,:]. Grid = 2 batch-groups x 64 col-WGs (16 h-cols each).
//   Per-step consumer read: 32KB (16 rows) instead of 64KB; sweep 8 loads
//   instead of 16; dependency width 64 WGs instead of 128; the two groups
//   run decoupled serial chains. M=16 MFMA stays full. Wh frags in regs
//   (bfrag[4][8] = 128 VGPR). Sentinel flag-free sync as R1/R3.
// ---------------------------------------------------------------------------

typedef short bf16x8 __attribute__((ext_vector_type(8)));
typedef float f32x4  __attribute__((ext_vector_type(4)));
typedef unsigned int uint4v __attribute__((ext_vector_type(4)));

#define MFMA16(a, b, c) __builtin_amdgcn_mfma_f32_16x16x32_bf16((a), (b), (c), 0, 0, 0)

__device__ __forceinline__ unsigned short f2bf(float f) {
    unsigned int u = __builtin_bit_cast(unsigned int, f);
    u = (u + 0x7FFFu + ((u >> 16) & 1u)) >> 16;   // RNE
    return (unsigned short)u;
}
__device__ __forceinline__ float bf2f(unsigned short h) {
    unsigned int u = ((unsigned int)h) << 16;
    return __builtin_bit_cast(float, u);
}
__device__ __forceinline__ float sigmoidf_(float x) { return 1.0f / (1.0f + __expf(-x)); }
__device__ __forceinline__ float tanhf_(float x)    { return 1.0f - 2.0f / (__expf(2.0f * x) + 1.0f); }

// ---------------------------------------------------------------------------
// Kernel 1: gx GEMM.  C[16384 x 4096] = X[16384 x 512] @ Wx[512 x 4096], bf16 out.
// (unchanged — scan dominates)
// ---------------------------------------------------------------------------
__global__ void __launch_bounds__(256) gx_gemm(
    const float* __restrict__ X,
    const float* __restrict__ Wf, const float* __restrict__ Wi,
    const float* __restrict__ Wo, const float* __restrict__ Wc,
    unsigned short* __restrict__ gxOut)
{
    __shared__ unsigned short As[128 * 40];
    __shared__ unsigned short Bs[128 * 40];

    const int tid  = threadIdx.x;
    const int lane = tid & 63;
    const int wid  = tid >> 6;
    const int lr   = lane & 15;
    const int lq   = lane >> 4;

    const int m0 = blockIdx.x * 128;
    const int n0 = blockIdx.y * 128;
    const float* Wg = (n0 < 1024) ? Wf : (n0 < 2048) ? Wi : (n0 < 3072) ? Wo : Wc;
    const int ncol0 = n0 & 1023;

    const int mw = (wid & 1) * 64;
    const int nw = (wid >> 1) * 64;

    f32x4 acc[4][4];
#pragma unroll
    for (int i = 0; i < 4; i++)
#pragma unroll
        for (int j = 0; j < 4; j++) acc[i][j] = (f32x4){0.f, 0.f, 0.f, 0.f};

    for (int k0 = 0; k0 < 512; k0 += 32) {
#pragma unroll
        for (int i = 0; i < 4; i++) {
            int s   = tid + i * 256;
            int row = s >> 3;
            int c4  = s & 7;
            float4 v = *(const float4*)(X + (size_t)(m0 + row) * 512 + k0 + c4 * 4);
            ushort4 h;
            h.x = f2bf(v.x); h.y = f2bf(v.y); h.z = f2bf(v.z); h.w = f2bf(v.w);
            *(ushort4*)(As + row * 40 + c4 * 4) = h;
        }
#pragma unroll
        for (int i = 0; i < 4; i++) {
            int s  = tid + i * 256;
            int kk = s >> 5;
            int c4 = s & 31;
            float4 v = *(const float4*)(Wg + (size_t)(k0 + kk) * 1024 + ncol0 + c4 * 4);
            Bs[(c4 * 4 + 0) * 40 + kk] = f2bf(v.x);
            Bs[(c4 * 4 + 1) * 40 + kk] = f2bf(v.y);
            Bs[(c4 * 4 + 2) * 40 + kk] = f2bf(v.z);
            Bs[(c4 * 4 + 3) * 40 + kk] = f2bf(v.w);
        }
        __syncthreads();

        bf16x8 af[4], bfr[4];
#pragma unroll
        for (int tm = 0; tm < 4; tm++)
            af[tm] = *(const bf16x8*)(As + (mw + tm * 16 + lr) * 40 + lq * 8);
#pragma unroll
        for (int tn = 0; tn < 4; tn++)
            bfr[tn] = *(const bf16x8*)(Bs + (nw + tn * 16 + lr) * 40 + lq * 8);
#pragma unroll
        for (int tm = 0; tm < 4; tm++)
#pragma unroll
            for (int tn = 0; tn < 4; tn++)
                acc[tm][tn] = MFMA16(af[tm], bfr[tn], acc[tm][tn]);
        __syncthreads();
    }

#pragma unroll
    for (int tm = 0; tm < 4; tm++)
#pragma unroll
        for (int tn = 0; tn < 4; tn++)
#pragma unroll
            for (int r = 0; r < 4; r++) {
                int row = m0 + mw + tm * 16 + lq * 4 + r;
                int col = n0 + nw + tn * 16 + lr;
                gxOut[(size_t)row * 4096 + col] = f2bf(acc[tm][tn][r]);
            }
}

// ---------------------------------------------------------------------------
// Kernel 2: persistent scan. 128 WGs x 256 threads.
//   WG w: bg = w>>6 (batch group: rows bg*16..+15), cg = w&63, j0 = cg*16.
//   Owns h-cols j0..j0+15 (gate cols g*16+jj, g=0..3) for its 16 batch rows.
//   Wave kq covers K [kq*256,+256) in 8 chunks of 32k; M=16 (full tile).
// LDS (dynamic):
//   glds  [2 buf][4 kq][64 col][20 row-pad] f32 partials        : 40960 B
//   blds  [64] f32                                              :   256 B
// Wh fragments in registers: bfrag[4 gate][8 ks] = 128 VGPR.
// ---------------------------------------------------------------------------
#define NWG 128
#define LDS2_BYTES 41216
#define GBUF 5120     // floats per glds buffer (4 * 64 * 20)
#define KSTR 1280     // floats per kq slice (64 * 20)
#define CSTR 20       // floats per col

__global__ void __launch_bounds__(256, 1) lstm_scan(
    const float* __restrict__ Whf, const float* __restrict__ Whi,
    const float* __restrict__ Who, const float* __restrict__ Whc,
    const float* __restrict__ Bf,  const float* __restrict__ Bi,
    const float* __restrict__ Bo,  const float* __restrict__ Bc,
    const unsigned short* __restrict__ gx,
    unsigned short* __restrict__ hhist,   // [512][32][1024] bf16, slot t = h_t
                                          // pre-filled 0xFF (sentinel)
    float* __restrict__ out)
{
    extern __shared__ char lds[];
    float* glds = (float*)lds;            // 40960 B
    float* blds = (float*)(lds + 40960);  //   256 B

    const int tid  = threadIdx.x;
    const int w    = blockIdx.x;
    const int bg   = w >> 6;            // batch group (0..1): rows bg*16..+15
    const int cg   = w & 63;            // col group
    const int j0   = cg * 16;
    const int lane = tid & 63;
    const int kq   = tid >> 6;          // wave id == K-split chunk
    const int lr   = lane & 15;
    const int lq   = lane >> 4;

    // ---- biases ----
    if (tid < 64) {
        int g = tid >> 4, jj = tid & 15;
        const float* bp = (g == 0) ? Bf : (g == 1) ? Bi : (g == 2) ? Bo : Bc;
        blds[tid] = bp[j0 + jj];
    }

    // ---- Wh B-fragments -> REGISTERS (constant over all t) ----
    // bfrag[g][ks][j] = W_g[(kq*256 + ks*32 + lq*8 + j)][j0 + lr]
    bf16x8 bfrag[4][8];
#pragma unroll
    for (int g = 0; g < 4; g++) {
        const float* wp = (g == 0) ? Whf : (g == 1) ? Whi : (g == 2) ? Who : Whc;
#pragma unroll
        for (int ks = 0; ks < 8; ks++) {
            int kbase = kq * 256 + ks * 32 + lq * 8;
            bf16x8 b;
#pragma unroll
            for (int j = 0; j < 8; j++)
                b[j] = (short)f2bf(wp[(size_t)(kbase + j) * 1024 + j0 + lr]);
            bfrag[g][ks] = b;
        }
    }

    const int cb = tid >> 4;            // epilogue batch row within group (0..15)
    const int cj = tid & 15;            // epilogue h-col within slice (0..15)
    const int b  = bg * 16 + cb;        // global batch row
    float c_reg = 0.f;

    __syncthreads();

    for (int t = 0; t < 512; t++) {
        float* gb = glds + (t & 1) * GBUF;

        // ---- prefetch gx for this step (overlaps the sentinel sweep) ----
        const unsigned short* gxr = gx + ((size_t)(b * 512 + t)) * 4096 + j0 + cj;
        float gxv[4];
#pragma unroll
        for (int g = 0; g < 4; g++) gxv[g] = bf2f(gxr[(size_t)g * 1024]);

        if (t > 0) {
            // ---- sentinel-sweep GEMM: rows bg*16+lr, K-quarter kq,
            //      8 chunks of 32k, retry dirty chunks, MFMA on arrival ----
            const unsigned short* hsrc = hhist + (size_t)t * 32768;

            f32x4 acc[4];
#pragma unroll
            for (int g = 0; g < 4; g++) acc[g] = (f32x4){0.f, 0.f, 0.f, 0.f};

            uint4v fa[8];
            unsigned int pend = 0xFFu;
            while (pend) {
#pragma unroll
                for (int ks = 0; ks < 8; ks++) {
                    if (pend & (1u << ks)) {
                        const unsigned short* p = hsrc + (bg * 16 + lr) * 1024
                                                   + kq * 256 + ks * 32 + lq * 8;
                        asm volatile("global_load_dwordx4 %0, %1, off sc0 sc1"
                                     : "=v"(fa[ks]) : "v"(p));
                    }
                }
                asm volatile("s_waitcnt vmcnt(0)" ::: "memory");
                __builtin_amdgcn_sched_barrier(0);

                unsigned int np = 0;
#pragma unroll
                for (int ks = 0; ks < 8; ks++) {
                    if (pend & (1u << ks)) {
                        uint4v u = fa[ks];
                        bool dirty = (u[0] == 0xFFFFFFFFu) | (u[1] == 0xFFFFFFFFu)
                                   | (u[2] == 0xFFFFFFFFu) | (u[3] == 0xFFFFFFFFu);
                        if (__any(dirty)) {
                            np |= 1u << ks;
                        } else {
                            bf16x8 a = __builtin_bit_cast(bf16x8, u);
                            acc[0] = MFMA16(a, bfrag[0][ks], acc[0]);
                            acc[1] = MFMA16(a, bfrag[1][ks], acc[1]);
                            acc[2] = MFMA16(a, bfrag[2][ks], acc[2]);
                            acc[3] = MFMA16(a, bfrag[3][ks], acc[3]);
                        }
                    }
                }
                pend = np;
            }

            // ---- partials -> glds[t&1][kq][col][row], f32x4 rows lq*4..+3 ----
            // C/D layout: row-in-tile = lq*4+r (batch), col = g*16+lr (gate col)
#pragma unroll
            for (int g = 0; g < 4; g++)
                *(f32x4*)(gb + kq * KSTR + (g * 16 + lr) * CSTR + lq * 4) = acc[g];
        }
        __syncthreads();   // barrier B: partials visible (the only barrier)

        // ---- pointwise epilogue: thread (cb, cj) ----
        float sg[4];
#pragma unroll
        for (int g = 0; g < 4; g++) {
            float dot = 0.f;
            if (t > 0) {
#pragma unroll
                for (int p = 0; p < 4; p++)
                    dot += gb[p * KSTR + (g * 16 + cj) * CSTR + cb];
            }
            sg[g] = sigmoidf_(dot + gxv[g] + blds[g * 16 + cj]);
        }
        float cn = sg[0] * c_reg + sg[1] * sg[3];   // f*c + i*sigmoid(cand)
        c_reg = cn;
        float hn = sg[2] * tanhf_(cn);

        if (t < 511) {
            // ---- h_{t+1}: gather 8 cols into sc1 dwordx4 (cj==0 and cj==8) ----
            unsigned int hb = (unsigned int)f2bf(hn);
            unsigned int nb = (unsigned int)__shfl_xor((int)hb, 1);
            unsigned int v  = (hb & 0xFFFFu) | (nb << 16);     // cols (cj, cj+1), even cj
            unsigned int v2 = (unsigned int)__shfl_xor((int)v, 2);
            unsigned int v4 = (unsigned int)__shfl_xor((int)v, 4);
            unsigned int v6 = (unsigned int)__shfl_xor((int)v2, 4);
            if ((cj & 7) == 0) {
                uint4v q;
                q[0] = v; q[1] = v2; q[2] = v4; q[3] = v6;     // cols cj..cj+7
                unsigned short* dst = hhist + (size_t)(t + 1) * 32768
                                      + b * 1024 + j0 + cj;
                asm volatile("global_store_dwordx4 %0, %1, off sc1"
                             :: "v"(dst), "v"(q) : "memory");
            }
            out[((size_t)b * 512 + t) * 1024 + j0 + cj] = sg[2];   // seq out = o gate
        } else {
            out[((size_t)b * 512 + t) * 1024 + j0 + cj] = sg[2];
            out[16777216 + b * 1024 + j0 + cj]          = hn;   // ht
            out[16777216 + 32768 + b * 1024 + j0 + cj]  = cn;   // ct
        }
        // no barrier D: glds double-buffered by t parity; cross-step reuse is
        // separated by barrier B + the global h-store data dependency.
    }
}

__global__ void ws_diag(float* out, float mb) { out[threadIdx.x] = -mb; }

extern "C" void kernel_launch(void* const* d_in, const int* in_sizes, int n_in,
                              void* d_out, int out_size, void* d_ws, size_t ws_size,
                              hipStream_t stream)
{
    const float* x   = (const float*)d_in[0];
    const float* wxf = (const float*)d_in[1];
    const float* whf = (const float*)d_in[2];
    const float* bhf = (const float*)d_in[3];
    const float* wxi = (const float*)d_in[4];
    const float* whi = (const float*)d_in[5];
    const float* bhi = (const float*)d_in[6];
    const float* wxo = (const float*)d_in[7];
    const float* who = (const float*)d_in[8];
    const float* bho = (const float*)d_in[9];
    const float* wxc = (const float*)d_in[10];
    const float* whc = (const float*)d_in[11];
    const float* bhc = (const float*)d_in[12];
    float* out = (float*)d_out;

    const size_t GX_BYTES = (size_t)16384 * 4096 * 2;    // 134217728
    const size_t HH_BYTES = (size_t)512 * 32 * 1024 * 2; //  33554432
    const size_t NEED = GX_BYTES + HH_BYTES;

    if (ws_size < NEED) {
        ws_diag<<<dim3(1), dim3(256), 0, stream>>>(out, (float)(ws_size >> 20));
        return;
    }

    unsigned short* gxbuf = (unsigned short*)d_ws;
    unsigned short* hh    = (unsigned short*)((char*)d_ws + GX_BYTES);

    (void)hipFuncSetAttribute((const void*)lstm_scan,
                              hipFuncAttributeMaxDynamicSharedMemorySize, LDS2_BYTES);

    gx_gemm<<<dim3(128, 32), dim3(256), 0, stream>>>(x, wxf, wxi, wxo, wxc, gxbuf);
    // sentinel-fill hhist: bf16 0xFFFF (-NaN) is unreachable for real h (|h|<1)
    hipMemsetAsync(hh, 0xFF, HH_BYTES, stream);
    lstm_scan<<<dim3(NWG), dim3(256), LDS2_BYTES, stream>>>(
        whf, whi, who, whc, bhf, bhi, bho, bhc, gxbuf, hh, out);
}

// Round 5
// 2440.272 us; speedup vs baseline: 3.2681x; 1.0766x over previous
//
#include <hip/hip_runtime.h>
#include <stdint.h>

// ---------------------------------------------------------------------------
// LSTM_14242111554073  (B=32, S=512, IN=512, H=1024, fp32 in/out)
// Phase 1: gx = x @ [wxf|wxi|wxo|wxc]  (bf16 MFMA GEMM, 16384x512x4096)
// Phase 2: persistent scan.
//   R5 change: 64 WGs x 512 thr = 2 batch-groups x 32 col-WGs (32 h-cols
//   each). Halves (again) the validated lever: per-group convergence width
//   64 -> 32 WGs, aggregate poll volume 4 -> 2 MB/sweep, per-wave sweep
//   8 -> 4 loads. 8 waves/WG, wave = K-eighth (128) x 128 gate cols
//   (bfrag[8 ct][4 ks] = 128 VGPR). 8-deep K-reduce in single-buffer glds
//   (2 barriers/step; R3 proved LDS micro-cost is off the critical path).
//   Flag-free sentinel sync as R1/R3/R4 (hhist prefilled 0xFF = bf16 -NaN).
// ---------------------------------------------------------------------------

typedef short bf16x8 __attribute__((ext_vector_type(8)));
typedef float f32x4  __attribute__((ext_vector_type(4)));
typedef unsigned int uint4v __attribute__((ext_vector_type(4)));

#define MFMA16(a, b, c) __builtin_amdgcn_mfma_f32_16x16x32_bf16((a), (b), (c), 0, 0, 0)

__device__ __forceinline__ unsigned short f2bf(float f) {
    unsigned int u = __builtin_bit_cast(unsigned int, f);
    u = (u + 0x7FFFu + ((u >> 16) & 1u)) >> 16;   // RNE
    return (unsigned short)u;
}
__device__ __forceinline__ float bf2f(unsigned short h) {
    unsigned int u = ((unsigned int)h) << 16;
    return __builtin_bit_cast(float, u);
}
__device__ __forceinline__ float sigmoidf_(float x) { return 1.0f / (1.0f + __expf(-x)); }
__device__ __forceinline__ float tanhf_(float x)    { return 1.0f - 2.0f / (__expf(2.0f * x) + 1.0f); }

// ---------------------------------------------------------------------------
// Kernel 1: gx GEMM.  C[16384 x 4096] = X[16384 x 512] @ Wx[512 x 4096], bf16 out.
// (unchanged — scan dominates)
// ---------------------------------------------------------------------------
__global__ void __launch_bounds__(256) gx_gemm(
    const float* __restrict__ X,
    const float* __restrict__ Wf, const float* __restrict__ Wi,
    const float* __restrict__ Wo, const float* __restrict__ Wc,
    unsigned short* __restrict__ gxOut)
{
    __shared__ unsigned short As[128 * 40];
    __shared__ unsigned short Bs[128 * 40];

    const int tid  = threadIdx.x;
    const int lane = tid & 63;
    const int wid  = tid >> 6;
    const int lr   = lane & 15;
    const int lq   = lane >> 4;

    const int m0 = blockIdx.x * 128;
    const int n0 = blockIdx.y * 128;
    const float* Wg = (n0 < 1024) ? Wf : (n0 < 2048) ? Wi : (n0 < 3072) ? Wo : Wc;
    const int ncol0 = n0 & 1023;

    const int mw = (wid & 1) * 64;
    const int nw = (wid >> 1) * 64;

    f32x4 acc[4][4];
#pragma unroll
    for (int i = 0; i < 4; i++)
#pragma unroll
        for (int j = 0; j < 4; j++) acc[i][j] = (f32x4){0.f, 0.f, 0.f, 0.f};

    for (int k0 = 0; k0 < 512; k0 += 32) {
#pragma unroll
        for (int i = 0; i < 4; i++) {
            int s   = tid + i * 256;
            int row = s >> 3;
            int c4  = s & 7;
            float4 v = *(const float4*)(X + (size_t)(m0 + row) * 512 + k0 + c4 * 4);
            ushort4 h;
            h.x = f2bf(v.x); h.y = f2bf(v.y); h.z = f2bf(v.z); h.w = f2bf(v.w);
            *(ushort4*)(As + row * 40 + c4 * 4) = h;
        }
#pragma unroll
        for (int i = 0; i < 4; i++) {
            int s  = tid + i * 256;
            int kk = s >> 5;
            int c4 = s & 31;
            float4 v = *(const float4*)(Wg + (size_t)(k0 + kk) * 1024 + ncol0 + c4 * 4);
            Bs[(c4 * 4 + 0) * 40 + kk] = f2bf(v.x);
            Bs[(c4 * 4 + 1) * 40 + kk] = f2bf(v.y);
            Bs[(c4 * 4 + 2) * 40 + kk] = f2bf(v.z);
            Bs[(c4 * 4 + 3) * 40 + kk] = f2bf(v.w);
        }
        __syncthreads();

        bf16x8 af[4], bfr[4];
#pragma unroll
        for (int tm = 0; tm < 4; tm++)
            af[tm] = *(const bf16x8*)(As + (mw + tm * 16 + lr) * 40 + lq * 8);
#pragma unroll
        for (int tn = 0; tn < 4; tn++)
            bfr[tn] = *(const bf16x8*)(Bs + (nw + tn * 16 + lr) * 40 + lq * 8);
#pragma unroll
        for (int tm = 0; tm < 4; tm++)
#pragma unroll
            for (int tn = 0; tn < 4; tn++)
                acc[tm][tn] = MFMA16(af[tm], bfr[tn], acc[tm][tn]);
        __syncthreads();
    }

#pragma unroll
    for (int tm = 0; tm < 4; tm++)
#pragma unroll
        for (int tn = 0; tn < 4; tn++)
#pragma unroll
            for (int r = 0; r < 4; r++) {
                int row = m0 + mw + tm * 16 + lq * 4 + r;
                int col = n0 + nw + tn * 16 + lr;
                gxOut[(size_t)row * 4096 + col] = f2bf(acc[tm][tn][r]);
            }
}

// ---------------------------------------------------------------------------
// Kernel 2: persistent scan. 64 WGs x 512 threads (8 waves).
//   WG w: bg = w&1 (batch group: rows bg*16..+15), cg = w>>1, j0 = cg*32.
//   Owns h-cols j0..j0+31 (gate cols c = g*32+jj, g=0..3) for 16 batch rows.
//   Wave kq (0..7) covers K [kq*128,+128) in 4 chunks of 32k; M=16 full.
// LDS (dynamic):
//   glds  [8 kq][128 col][20 row-pad] f32 partials              : 81920 B
//   blds  [128] f32                                             :   512 B
// total 82432 B -> 1 WG/CU. Wh frags in regs: bfrag[8 ct][4 ks] = 128 VGPR.
// ---------------------------------------------------------------------------
#define NWG 64
#define LDS2_BYTES 82432
#define KSTR 2560     // floats per kq slice (128 * 20)
#define CSTR 20       // floats per col

__global__ void __launch_bounds__(512, 1) lstm_scan(
    const float* __restrict__ Whf, const float* __restrict__ Whi,
    const float* __restrict__ Who, const float* __restrict__ Whc,
    const float* __restrict__ Bf,  const float* __restrict__ Bi,
    const float* __restrict__ Bo,  const float* __restrict__ Bc,
    const unsigned short* __restrict__ gx,
    unsigned short* __restrict__ hhist,   // [512][32][1024] bf16, slot t = h_t
                                          // pre-filled 0xFF (sentinel)
    float* __restrict__ out)
{
    extern __shared__ char lds[];
    float* glds = (float*)lds;            // 81920 B
    float* blds = (float*)(lds + 81920);  //   512 B

    const int tid  = threadIdx.x;
    const int w    = blockIdx.x;
    const int bg   = w & 1;             // batch group: rows bg*16..+15
    const int cg   = w >> 1;            // col group
    const int j0   = cg * 32;
    const int lane = tid & 63;
    const int kq   = tid >> 6;          // wave id == K-eighth
    const int lr   = lane & 15;
    const int lq   = lane >> 4;

    // ---- biases (128 gate cols: c = g*32 + jj) ----
    if (tid < 128) {
        int g = tid >> 5, jj = tid & 31;
        const float* bp = (g == 0) ? Bf : (g == 1) ? Bi : (g == 2) ? Bo : Bc;
        blds[tid] = bp[j0 + jj];
    }

    // ---- Wh B-fragments -> REGISTERS (constant over all t) ----
    // bfrag[ct][ks][j] = W_g[(kq*128 + ks*32 + lq*8 + j)][j0 + jj]
    // where c = ct*16 + lr, g = c>>5, jj = c&31
    bf16x8 bfrag[8][4];
#pragma unroll
    for (int ct = 0; ct < 8; ct++) {
        int c = ct * 16 + lr;
        int g = c >> 5, jj = c & 31;
        const float* wp = (g == 0) ? Whf : (g == 1) ? Whi : (g == 2) ? Who : Whc;
#pragma unroll
        for (int ks = 0; ks < 4; ks++) {
            int kbase = kq * 128 + ks * 32 + lq * 8;
            bf16x8 b;
#pragma unroll
            for (int j = 0; j < 8; j++)
                b[j] = (short)f2bf(wp[(size_t)(kbase + j) * 1024 + j0 + jj]);
            bfrag[ct][ks] = b;
        }
    }

    const int cb = tid >> 5;            // epilogue batch row within group (0..15)
    const int cj = tid & 31;            // epilogue h-col within slice (0..31)
    const int b  = bg * 16 + cb;        // global batch row
    float c_reg = 0.f;

    __syncthreads();

    for (int t = 0; t < 512; t++) {
        // ---- prefetch gx for this step (overlaps the sentinel sweep) ----
        const unsigned short* gxr = gx + ((size_t)(b * 512 + t)) * 4096 + j0 + cj;
        float gxv[4];
#pragma unroll
        for (int g = 0; g < 4; g++) gxv[g] = bf2f(gxr[(size_t)g * 1024]);

        if (t > 0) {
            // ---- sentinel-sweep GEMM: rows bg*16+lr, K-eighth kq,
            //      4 chunks of 32k, retry dirty chunks, MFMA on arrival ----
            const unsigned short* hsrc = hhist + (size_t)t * 32768;

            f32x4 acc[8];
#pragma unroll
            for (int ct = 0; ct < 8; ct++) acc[ct] = (f32x4){0.f, 0.f, 0.f, 0.f};

            uint4v fa[4];
            unsigned int pend = 0xFu;
            while (pend) {
#pragma unroll
                for (int ks = 0; ks < 4; ks++) {
                    if (pend & (1u << ks)) {
                        const unsigned short* p = hsrc + (bg * 16 + lr) * 1024
                                                   + kq * 128 + ks * 32 + lq * 8;
                        asm volatile("global_load_dwordx4 %0, %1, off sc0 sc1"
                                     : "=v"(fa[ks]) : "v"(p));
                    }
                }
                asm volatile("s_waitcnt vmcnt(0)" ::: "memory");
                __builtin_amdgcn_sched_barrier(0);

                unsigned int np = 0;
#pragma unroll
                for (int ks = 0; ks < 4; ks++) {
                    if (pend & (1u << ks)) {
                        uint4v u = fa[ks];
                        bool dirty = (u[0] == 0xFFFFFFFFu) | (u[1] == 0xFFFFFFFFu)
                                   | (u[2] == 0xFFFFFFFFu) | (u[3] == 0xFFFFFFFFu);
                        if (__any(dirty)) {
                            np |= 1u << ks;
                        } else {
                            bf16x8 a = __builtin_bit_cast(bf16x8, u);
#pragma unroll
                            for (int ct = 0; ct < 8; ct++)
                                acc[ct] = MFMA16(a, bfrag[ct][ks], acc[ct]);
                        }
                    }
                }
                pend = np;
            }

            // ---- partials -> glds[kq][col][row], f32x4 rows lq*4..+3 ----
            // C/D layout: row-in-tile = lq*4+r (batch), col = ct*16+lr
#pragma unroll
            for (int ct = 0; ct < 8; ct++)
                *(f32x4*)(glds + kq * KSTR + (ct * 16 + lr) * CSTR + lq * 4)
                    = acc[ct];
        }
        __syncthreads();   // barrier B: partials visible

        // ---- pointwise epilogue: thread (cb, cj) ----
        float sg[4];
#pragma unroll
        for (int g = 0; g < 4; g++) {
            float dot = 0.f;
            if (t > 0) {
#pragma unroll
                for (int p = 0; p < 8; p++)
                    dot += glds[p * KSTR + (g * 32 + cj) * CSTR + cb];
            }
            sg[g] = sigmoidf_(dot + gxv[g] + blds[g * 32 + cj]);
        }
        float cn = sg[0] * c_reg + sg[1] * sg[3];   // f*c + i*sigmoid(cand)
        c_reg = cn;
        float hn = sg[2] * tanhf_(cn);

        if (t < 511) {
            // ---- h_{t+1}: gather 8 cols into sc1 dwordx4 (cj%8==0 lanes) ----
            unsigned int hb = (unsigned int)f2bf(hn);
            unsigned int nb = (unsigned int)__shfl_xor((int)hb, 1);
            unsigned int v  = (hb & 0xFFFFu) | (nb << 16);     // cols (cj, cj+1), even cj
            unsigned int v2 = (unsigned int)__shfl_xor((int)v, 2);
            unsigned int v4 = (unsigned int)__shfl_xor((int)v, 4);
            unsigned int v6 = (unsigned int)__shfl_xor((int)v2, 4);
            if ((cj & 7) == 0) {
                uint4v q;
                q[0] = v; q[1] = v2; q[2] = v4; q[3] = v6;     // cols cj..cj+7
                unsigned short* dst = hhist + (size_t)(t + 1) * 32768
                                      + b * 1024 + j0 + cj;
                asm volatile("global_store_dwordx4 %0, %1, off sc1"
                             :: "v"(dst), "v"(q) : "memory");
            }
            out[((size_t)b * 512 + t) * 1024 + j0 + cj] = sg[2];   // seq out = o gate
        } else {
            out[((size_t)b * 512 + t) * 1024 + j0 + cj] = sg[2];
            out[16777216 + b * 1024 + j0 + cj]          = hn;   // ht
            out[16777216 + 32768 + b * 1024 + j0 + cj]  = cn;   // ct
        }
        __syncthreads();   // barrier D: glds consumed before next step's writes
    }
}

__global__ void ws_diag(float* out, float mb) { out[threadIdx.x] = -mb; }

extern "C" void kernel_launch(void* const* d_in, const int* in_sizes, int n_in,
                              void* d_out, int out_size, void* d_ws, size_t ws_size,
                              hipStream_t stream)
{
    const float* x   = (const float*)d_in[0];
    const float* wxf = (const float*)d_in[1];
    const float* whf = (const float*)d_in[2];
    const float* bhf = (const float*)d_in[3];
    const float* wxi = (const float*)d_in[4];
    const float* whi = (const float*)d_in[5];
    const float* bhi = (const float*)d_in[6];
    const float* wxo = (const float*)d_in[7];
    const float* who = (const float*)d_in[8];
    const float* bho = (const float*)d_in[9];
    const float* wxc = (const float*)d_in[10];
    const float* whc = (const float*)d_in[11];
    const float* bhc = (const float*)d_in[12];
    float* out = (float*)d_out;

    const size_t GX_BYTES = (size_t)16384 * 4096 * 2;    // 134217728
    const size_t HH_BYTES = (size_t)512 * 32 * 1024 * 2; //  33554432
    const size_t NEED = GX_BYTES + HH_BYTES;

    if (ws_size < NEED) {
        ws_diag<<<dim3(1), dim3(256), 0, stream>>>(out, (float)(ws_size >> 20));
        return;
    }

    unsigned short* gxbuf = (unsigned short*)d_ws;
    unsigned short* hh    = (unsigned short*)((char*)d_ws + GX_BYTES);

    (void)hipFuncSetAttribute((const void*)lstm_scan,
                              hipFuncAttributeMaxDynamicSharedMemorySize, LDS2_BYTES);

    gx_gemm<<<dim3(128, 32), dim3(256), 0, stream>>>(x, wxf, wxi, wxo, wxc, gxbuf);
    // sentinel-fill hhist: bf16 0xFFFF (-NaN) is unreachable for real h (|h|<1)
    hipMemsetAsync(hh, 0xFF, HH_BYTES, stream);
    lstm_scan<<<dim3(NWG), dim3(512), LDS2_BYTES, stream>>>(
        whf, whi, who, whc, bhf, bhi, bho, bhc, gxbuf, hh, out);
}

// Round 8
// 2239.778 us; speedup vs baseline: 3.5606x; 1.0895x over previous
//
#include <hip/hip_runtime.h>
#include <stdint.h>

// ---------------------------------------------------------------------------
// LSTM_14242111554073  (B=32, S=512, IN=512, H=1024, fp32 in/out)
// R8: retreat from fusion (R6/R7 NaN — concurrent-gx protocol unproven);
//     back to R5's two-phase structure (proven 2440us) with FAST phase 1:
//   prep      : X -> Xb bf16 (flat), Wx -> WbT[4096][512] bf16 transposed
//               (LDS tile transpose). Xb/WbT live in the hhist workspace
//               region (20MB < 32MB), consumed before the 0xFF memset.
//   gx_gemm2  : same proven tile/fragment/MFMA core as gx_gemm, staging
//               replaced by 16B vector copies (no f2bf, no scatter; B^T rows
//               land directly in the col-major Bs layout). gx bit-identical.
//   lstm_scan : EXACT R5 kernel (proven 2033us, passed).
// ---------------------------------------------------------------------------

typedef short bf16x8 __attribute__((ext_vector_type(8)));
typedef float f32x4  __attribute__((ext_vector_type(4)));
typedef unsigned int uint4v __attribute__((ext_vector_type(4)));

#define MFMA16(a, b, c) __builtin_amdgcn_mfma_f32_16x16x32_bf16((a), (b), (c), 0, 0, 0)

__device__ __forceinline__ unsigned short f2bf(float f) {
    unsigned int u = __builtin_bit_cast(unsigned int, f);
    u = (u + 0x7FFFu + ((u >> 16) & 1u)) >> 16;   // RNE
    return (unsigned short)u;
}
__device__ __forceinline__ float bf2f(unsigned short h) {
    unsigned int u = ((unsigned int)h) << 16;
    return __builtin_bit_cast(float, u);
}
__device__ __forceinline__ float sigmoidf_(float x) { return 1.0f / (1.0f + __expf(-x)); }
__device__ __forceinline__ float tanhf_(float x)    { return 1.0f - 2.0f / (__expf(2.0f * x) + 1.0f); }

// ---------------------------------------------------------------------------
// Kernel 0: prep. blockIdx < 4096: Xb convert (2048 elems/WG).
//           blockIdx >= 4096: W transpose, 64x64 f32 tile per WG.
// ---------------------------------------------------------------------------
__global__ void __launch_bounds__(256) prep(
    const float* __restrict__ X,
    const float* __restrict__ Wf, const float* __restrict__ Wi,
    const float* __restrict__ Wo, const float* __restrict__ Wc,
    unsigned short* __restrict__ Xb,     // [16384*512] bf16
    unsigned short* __restrict__ WbT)    // [4096][512] bf16, row n = W_{n>>10}[:, n&1023]
{
    __shared__ unsigned short T[64][72];   // 9216 B (transpose tile, 144B rows)
    const int tid = threadIdx.x;
    int bid = blockIdx.x;

    if (bid < 4096) {
        size_t s = ((size_t)bid * 256 + tid) * 8;
        float4 v0 = *(const float4*)(X + s);
        float4 v1 = *(const float4*)(X + s + 4);
        unsigned int p0 = (unsigned int)f2bf(v0.x) | ((unsigned int)f2bf(v0.y) << 16);
        unsigned int p1 = (unsigned int)f2bf(v0.z) | ((unsigned int)f2bf(v0.w) << 16);
        unsigned int p2 = (unsigned int)f2bf(v1.x) | ((unsigned int)f2bf(v1.y) << 16);
        unsigned int p3 = (unsigned int)f2bf(v1.z) | ((unsigned int)f2bf(v1.w) << 16);
        uint4v q; q[0] = p0; q[1] = p1; q[2] = p2; q[3] = p3;
        *(uint4v*)(Xb + s) = q;
        return;
    }

    bid -= 4096;                 // 0..511
    const int gate = bid >> 7;   // 0..3
    const int r    = bid & 127;
    const int n0   = (r >> 3) * 64;   // 0..960  (col tile within gate)
    const int k0   = (r & 7) * 64;    // 0..448  (row tile)
    const float* Wg = (gate == 0) ? Wf : (gate == 1) ? Wi : (gate == 2) ? Wo : Wc;

    // read 64(k) x 64(n) f32 coalesced, store transposed into T[n][k]
#pragma unroll
    for (int it = 0; it < 4; it++) {
        int s  = tid + it * 256;     // 0..1023
        int kr = s >> 4;             // 0..63
        int c4 = s & 15;             // 0..15
        float4 v = *(const float4*)(Wg + (size_t)(k0 + kr) * 1024 + n0 + c4 * 4);
        T[c4 * 4 + 0][kr] = f2bf(v.x);
        T[c4 * 4 + 1][kr] = f2bf(v.y);
        T[c4 * 4 + 2][kr] = f2bf(v.z);
        T[c4 * 4 + 3][kr] = f2bf(v.w);
    }
    __syncthreads();
    // write WbT rows coalesced (16B per thread)
#pragma unroll
    for (int it = 0; it < 2; it++) {
        int s   = tid + it * 256;    // 0..511
        int nr  = s >> 3;            // 0..63
        int seg = s & 7;             // 0..7
        uint4v q = *(const uint4v*)&T[nr][seg * 8];
        *(uint4v*)(WbT + ((size_t)gate * 1024 + n0 + nr) * 512 + k0 + seg * 8) = q;
    }
}

// ---------------------------------------------------------------------------
// Kernel 1: gx GEMM (bf16 inputs).  C[16384 x 4096] = Xb @ WbT^T, bf16 out.
// Tile/fragment/MFMA/epilogue identical to the proven gx_gemm; staging is
// pure 16B vector copies into the same As[row][40] / Bs[col][40] layouts.
// ---------------------------------------------------------------------------
__global__ void __launch_bounds__(256) gx_gemm2(
    const unsigned short* __restrict__ Xb,   // [16384][512]
    const unsigned short* __restrict__ WbT,  // [4096][512]
    unsigned short* __restrict__ gxOut)
{
    __shared__ unsigned short As[128 * 40];
    __shared__ unsigned short Bs[128 * 40];

    const int tid  = threadIdx.x;
    const int lane = tid & 63;
    const int wid  = tid >> 6;
    const int lr   = lane & 15;
    const int lq   = lane >> 4;

    const int m0 = blockIdx.x * 128;
    const int n0 = blockIdx.y * 128;     // global gate-col 0..3968

    const int mw = (wid & 1) * 64;
    const int nw = (wid >> 1) * 64;

    f32x4 acc[4][4];
#pragma unroll
    for (int i = 0; i < 4; i++)
#pragma unroll
        for (int j = 0; j < 4; j++) acc[i][j] = (f32x4){0.f, 0.f, 0.f, 0.f};

    for (int k0 = 0; k0 < 512; k0 += 32) {
#pragma unroll
        for (int it = 0; it < 2; it++) {
            int s   = tid + it * 256;    // 0..511
            int row = s >> 2;            // 0..127
            int seg = s & 3;             // 0..3 (8 ush each)
            uint4v va = *(const uint4v*)(Xb + (size_t)(m0 + row) * 512 + k0 + seg * 8);
            *(uint4v*)(As + row * 40 + seg * 8) = va;
            uint4v vb = *(const uint4v*)(WbT + (size_t)(n0 + row) * 512 + k0 + seg * 8);
            *(uint4v*)(Bs + row * 40 + seg * 8) = vb;
        }
        __syncthreads();

        bf16x8 af[4], bfr[4];
#pragma unroll
        for (int tm = 0; tm < 4; tm++)
            af[tm] = *(const bf16x8*)(As + (mw + tm * 16 + lr) * 40 + lq * 8);
#pragma unroll
        for (int tn = 0; tn < 4; tn++)
            bfr[tn] = *(const bf16x8*)(Bs + (nw + tn * 16 + lr) * 40 + lq * 8);
#pragma unroll
        for (int tm = 0; tm < 4; tm++)
#pragma unroll
            for (int tn = 0; tn < 4; tn++)
                acc[tm][tn] = MFMA16(af[tm], bfr[tn], acc[tm][tn]);
        __syncthreads();
    }

#pragma unroll
    for (int tm = 0; tm < 4; tm++)
#pragma unroll
        for (int tn = 0; tn < 4; tn++)
#pragma unroll
            for (int r = 0; r < 4; r++) {
                int row = m0 + mw + tm * 16 + lq * 4 + r;
                int col = n0 + nw + tn * 16 + lr;
                gxOut[(size_t)row * 4096 + col] = f2bf(acc[tm][tn][r]);
            }
}

// ---------------------------------------------------------------------------
// Kernel 2: persistent scan — EXACT R5 kernel (proven). 64 WGs x 512 threads.
//   WG w: bg = w&1 (rows bg*16..+15), cg = w>>1, j0 = cg*32.
//   Wave kq (0..7) covers K [kq*128,+128) in 4 chunks of 32k; M=16 full.
// LDS: glds [8 kq][128 col][20 pad] f32 = 81920 B; blds [128] f32 = 512 B.
// ---------------------------------------------------------------------------
#define NWG_SCAN 64
#define LDS2_BYTES 82432
#define KSTR 2560
#define CSTR 20

__global__ void __launch_bounds__(512, 1) lstm_scan(
    const float* __restrict__ Whf, const float* __restrict__ Whi,
    const float* __restrict__ Who, const float* __restrict__ Whc,
    const float* __restrict__ Bf,  const float* __restrict__ Bi,
    const float* __restrict__ Bo,  const float* __restrict__ Bc,
    const unsigned short* __restrict__ gx,
    unsigned short* __restrict__ hhist,   // [512][32][1024] bf16, prefilled 0xFF
    float* __restrict__ out)
{
    extern __shared__ char lds[];
    float* glds = (float*)lds;            // 81920 B
    float* blds = (float*)(lds + 81920);  //   512 B

    const int tid  = threadIdx.x;
    const int w    = blockIdx.x;
    const int bg   = w & 1;
    const int cg   = w >> 1;
    const int j0   = cg * 32;
    const int lane = tid & 63;
    const int kq   = tid >> 6;
    const int lr   = lane & 15;
    const int lq   = lane >> 4;

    if (tid < 128) {
        int g = tid >> 5, jj = tid & 31;
        const float* bp = (g == 0) ? Bf : (g == 1) ? Bi : (g == 2) ? Bo : Bc;
        blds[tid] = bp[j0 + jj];
    }

    bf16x8 bfrag[8][4];
#pragma unroll
    for (int ct = 0; ct < 8; ct++) {
        int c = ct * 16 + lr;
        int g = c >> 5, jj = c & 31;
        const float* wp = (g == 0) ? Whf : (g == 1) ? Whi : (g == 2) ? Who : Whc;
#pragma unroll
        for (int ks = 0; ks < 4; ks++) {
            int kbase = kq * 128 + ks * 32 + lq * 8;
            bf16x8 b;
#pragma unroll
            for (int j = 0; j < 8; j++)
                b[j] = (short)f2bf(wp[(size_t)(kbase + j) * 1024 + j0 + jj]);
            bfrag[ct][ks] = b;
        }
    }

    const int cb = tid >> 5;
    const int cj = tid & 31;
    const int b  = bg * 16 + cb;
    float c_reg = 0.f;

    __syncthreads();

    for (int t = 0; t < 512; t++) {
        const unsigned short* gxr = gx + ((size_t)(b * 512 + t)) * 4096 + j0 + cj;
        float gxv[4];
#pragma unroll
        for (int g = 0; g < 4; g++) gxv[g] = bf2f(gxr[(size_t)g * 1024]);

        if (t > 0) {
            const unsigned short* hsrc = hhist + (size_t)t * 32768;

            f32x4 acc[8];
#pragma unroll
            for (int ct = 0; ct < 8; ct++) acc[ct] = (f32x4){0.f, 0.f, 0.f, 0.f};

            uint4v fa[4];
            unsigned int pend = 0xFu;
            while (pend) {
#pragma unroll
                for (int ks = 0; ks < 4; ks++) {
                    if (pend & (1u << ks)) {
                        const unsigned short* p = hsrc + (bg * 16 + lr) * 1024
                                                   + kq * 128 + ks * 32 + lq * 8;
                        asm volatile("global_load_dwordx4 %0, %1, off sc0 sc1"
                                     : "=v"(fa[ks]) : "v"(p));
                    }
                }
                asm volatile("s_waitcnt vmcnt(0)" ::: "memory");
                __builtin_amdgcn_sched_barrier(0);

                unsigned int np = 0;
#pragma unroll
                for (int ks = 0; ks < 4; ks++) {
                    if (pend & (1u << ks)) {
                        uint4v u = fa[ks];
                        bool dirty = (u[0] == 0xFFFFFFFFu) | (u[1] == 0xFFFFFFFFu)
                                   | (u[2] == 0xFFFFFFFFu) | (u[3] == 0xFFFFFFFFu);
                        if (__any(dirty)) {
                            np |= 1u << ks;
                        } else {
                            bf16x8 a = __builtin_bit_cast(bf16x8, u);
#pragma unroll
                            for (int ct = 0; ct < 8; ct++)
                                acc[ct] = MFMA16(a, bfrag[ct][ks], acc[ct]);
                        }
                    }
                }
                pend = np;
            }

#pragma unroll
            for (int ct = 0; ct < 8; ct++)
                *(f32x4*)(glds + kq * KSTR + (ct * 16 + lr) * CSTR + lq * 4)
                    = acc[ct];
        }
        __syncthreads();   // barrier B

        float sg[4];
#pragma unroll
        for (int g = 0; g < 4; g++) {
            float dot = 0.f;
            if (t > 0) {
#pragma unroll
                for (int p = 0; p < 8; p++)
                    dot += glds[p * KSTR + (g * 32 + cj) * CSTR + cb];
            }
            sg[g] = sigmoidf_(dot + gxv[g] + blds[g * 32 + cj]);
        }
        float cn = sg[0] * c_reg + sg[1] * sg[3];
        c_reg = cn;
        float hn = sg[2] * tanhf_(cn);

        if (t < 511) {
            unsigned int hb = (unsigned int)f2bf(hn);
            unsigned int nb = (unsigned int)__shfl_xor((int)hb, 1);
            unsigned int v  = (hb & 0xFFFFu) | (nb << 16);
            unsigned int v2 = (unsigned int)__shfl_xor((int)v, 2);
            unsigned int v4 = (unsigned int)__shfl_xor((int)v, 4);
            unsigned int v6 = (unsigned int)__shfl_xor((int)v2, 4);
            if ((cj & 7) == 0) {
                uint4v q;
                q[0] = v; q[1] = v2; q[2] = v4; q[3] = v6;
                unsigned short* dst = hhist + (size_t)(t + 1) * 32768
                                      + b * 1024 + j0 + cj;
                asm volatile("global_store_dwordx4 %0, %1, off sc1"
                             :: "v"(dst), "v"(q) : "memory");
            }
            out[((size_t)b * 512 + t) * 1024 + j0 + cj] = sg[2];
        } else {
            out[((size_t)b * 512 + t) * 1024 + j0 + cj] = sg[2];
            out[16777216 + b * 1024 + j0 + cj]          = hn;   // ht
            out[16777216 + 32768 + b * 1024 + j0 + cj]  = cn;   // ct
        }
        __syncthreads();   // barrier D
    }
}

__global__ void ws_diag(float* out, float mb) { out[threadIdx.x] = -mb; }

extern "C" void kernel_launch(void* const* d_in, const int* in_sizes, int n_in,
                              void* d_out, int out_size, void* d_ws, size_t ws_size,
                              hipStream_t stream)
{
    const float* x   = (const float*)d_in[0];
    const float* wxf = (const float*)d_in[1];
    const float* whf = (const float*)d_in[2];
    const float* bhf = (const float*)d_in[3];
    const float* wxi = (const float*)d_in[4];
    const float* whi = (const float*)d_in[5];
    const float* bhi = (const float*)d_in[6];
    const float* wxo = (const float*)d_in[7];
    const float* who = (const float*)d_in[8];
    const float* bho = (const float*)d_in[9];
    const float* wxc = (const float*)d_in[10];
    const float* whc = (const float*)d_in[11];
    const float* bhc = (const float*)d_in[12];
    float* out = (float*)d_out;

    const size_t GX_BYTES = (size_t)16384 * 4096 * 2;    // 134217728
    const size_t HH_BYTES = (size_t)512 * 32 * 1024 * 2; //  33554432
    const size_t NEED = GX_BYTES + HH_BYTES;

    if (ws_size < NEED) {
        ws_diag<<<dim3(1), dim3(256), 0, stream>>>(out, (float)(ws_size >> 20));
        return;
    }

    unsigned short* gxbuf = (unsigned short*)d_ws;
    unsigned short* hh    = (unsigned short*)((char*)d_ws + GX_BYTES);
    // Xb (16MB) + WbT (4MB) borrow the hhist region; consumed before memset.
    unsigned short* Xb  = hh;
    unsigned short* WbT = hh + 8388608;   // +16MB

    (void)hipFuncSetAttribute((const void*)lstm_scan,
                              hipFuncAttributeMaxDynamicSharedMemorySize, LDS2_BYTES);

    prep<<<dim3(4608), dim3(256), 0, stream>>>(x, wxf, wxi, wxo, wxc, Xb, WbT);
    gx_gemm2<<<dim3(128, 32), dim3(256), 0, stream>>>(Xb, WbT, gxbuf);
    // sentinel-fill hhist (destroys Xb/WbT — already consumed)
    hipMemsetAsync(hh, 0xFF, HH_BYTES, stream);
    lstm_scan<<<dim3(NWG_SCAN), dim3(512), LDS2_BYTES, stream>>>(
        whf, whi, who, whc, bhf, bhi, bho, bhc, gxbuf, hh, out);
}

// Round 9
// 2227.256 us; speedup vs baseline: 3.5807x; 1.0056x over previous
//
#include <hip/hip_runtime.h>
#include <stdint.h>

// ---------------------------------------------------------------------------
// LSTM_14242111554073  (B=32, S=512, IN=512, H=1024, fp32 in/out)
// R9 = R8 + ONE knob: scan barriers B/D -> raw s_barrier with explicit
//   compiler fences (asm memory clobber both sides + sched_barrier(0)) and
//   lgkmcnt(0) before B. Removes the per-step implicit vmcnt(0) drain of the
//   h sc1 store + out stores (~1 LLC store-RT/step); the next sweep's own
//   vmcnt(0) absorbs the drain overlapped with its load RT.
//   R7 exonerated this swap (R7 NaN'd WITH __syncthreads -> the R6 NaN was
//   the concurrent-gx path, not the barrier). This round tests it isolated.
// Phase 1 (proven R8): prep (X->bf16, Wx->WbT transpose) + gx_gemm2
//   (16B vector staging, bit-identical gx). Scan protocol otherwise = R5.
// ---------------------------------------------------------------------------

typedef short bf16x8 __attribute__((ext_vector_type(8)));
typedef float f32x4  __attribute__((ext_vector_type(4)));
typedef unsigned int uint4v __attribute__((ext_vector_type(4)));

#define MFMA16(a, b, c) __builtin_amdgcn_mfma_f32_16x16x32_bf16((a), (b), (c), 0, 0, 0)

__device__ __forceinline__ unsigned short f2bf(float f) {
    unsigned int u = __builtin_bit_cast(unsigned int, f);
    u = (u + 0x7FFFu + ((u >> 16) & 1u)) >> 16;   // RNE
    return (unsigned short)u;
}
__device__ __forceinline__ float bf2f(unsigned short h) {
    unsigned int u = ((unsigned int)h) << 16;
    return __builtin_bit_cast(float, u);
}
__device__ __forceinline__ float sigmoidf_(float x) { return 1.0f / (1.0f + __expf(-x)); }
__device__ __forceinline__ float tanhf_(float x)    { return 1.0f - 2.0f / (__expf(2.0f * x) + 1.0f); }

// ---------------------------------------------------------------------------
// Kernel 0: prep. blockIdx < 4096: Xb convert (2048 elems/WG).
//           blockIdx >= 4096: W transpose, 64x64 f32 tile per WG.
// ---------------------------------------------------------------------------
__global__ void __launch_bounds__(256) prep(
    const float* __restrict__ X,
    const float* __restrict__ Wf, const float* __restrict__ Wi,
    const float* __restrict__ Wo, const float* __restrict__ Wc,
    unsigned short* __restrict__ Xb,     // [16384*512] bf16
    unsigned short* __restrict__ WbT)    // [4096][512] bf16
{
    __shared__ unsigned short T[64][72];
    const int tid = threadIdx.x;
    int bid = blockIdx.x;

    if (bid < 4096) {
        size_t s = ((size_t)bid * 256 + tid) * 8;
        float4 v0 = *(const float4*)(X + s);
        float4 v1 = *(const float4*)(X + s + 4);
        unsigned int p0 = (unsigned int)f2bf(v0.x) | ((unsigned int)f2bf(v0.y) << 16);
        unsigned int p1 = (unsigned int)f2bf(v0.z) | ((unsigned int)f2bf(v0.w) << 16);
        unsigned int p2 = (unsigned int)f2bf(v1.x) | ((unsigned int)f2bf(v1.y) << 16);
        unsigned int p3 = (unsigned int)f2bf(v1.z) | ((unsigned int)f2bf(v1.w) << 16);
        uint4v q; q[0] = p0; q[1] = p1; q[2] = p2; q[3] = p3;
        *(uint4v*)(Xb + s) = q;
        return;
    }

    bid -= 4096;
    const int gate = bid >> 7;
    const int r    = bid & 127;
    const int n0   = (r >> 3) * 64;
    const int k0   = (r & 7) * 64;
    const float* Wg = (gate == 0) ? Wf : (gate == 1) ? Wi : (gate == 2) ? Wo : Wc;

#pragma unroll
    for (int it = 0; it < 4; it++) {
        int s  = tid + it * 256;
        int kr = s >> 4;
        int c4 = s & 15;
        float4 v = *(const float4*)(Wg + (size_t)(k0 + kr) * 1024 + n0 + c4 * 4);
        T[c4 * 4 + 0][kr] = f2bf(v.x);
        T[c4 * 4 + 1][kr] = f2bf(v.y);
        T[c4 * 4 + 2][kr] = f2bf(v.z);
        T[c4 * 4 + 3][kr] = f2bf(v.w);
    }
    __syncthreads();
#pragma unroll
    for (int it = 0; it < 2; it++) {
        int s   = tid + it * 256;
        int nr  = s >> 3;
        int seg = s & 7;
        uint4v q = *(const uint4v*)&T[nr][seg * 8];
        *(uint4v*)(WbT + ((size_t)gate * 1024 + n0 + nr) * 512 + k0 + seg * 8) = q;
    }
}

// ---------------------------------------------------------------------------
// Kernel 1: gx GEMM (bf16 inputs).  C[16384 x 4096] = Xb @ WbT^T, bf16 out.
// ---------------------------------------------------------------------------
__global__ void __launch_bounds__(256) gx_gemm2(
    const unsigned short* __restrict__ Xb,   // [16384][512]
    const unsigned short* __restrict__ WbT,  // [4096][512]
    unsigned short* __restrict__ gxOut)
{
    __shared__ unsigned short As[128 * 40];
    __shared__ unsigned short Bs[128 * 40];

    const int tid  = threadIdx.x;
    const int lane = tid & 63;
    const int wid  = tid >> 6;
    const int lr   = lane & 15;
    const int lq   = lane >> 4;

    const int m0 = blockIdx.x * 128;
    const int n0 = blockIdx.y * 128;

    const int mw = (wid & 1) * 64;
    const int nw = (wid >> 1) * 64;

    f32x4 acc[4][4];
#pragma unroll
    for (int i = 0; i < 4; i++)
#pragma unroll
        for (int j = 0; j < 4; j++) acc[i][j] = (f32x4){0.f, 0.f, 0.f, 0.f};

    for (int k0 = 0; k0 < 512; k0 += 32) {
#pragma unroll
        for (int it = 0; it < 2; it++) {
            int s   = tid + it * 256;
            int row = s >> 2;
            int seg = s & 3;
            uint4v va = *(const uint4v*)(Xb + (size_t)(m0 + row) * 512 + k0 + seg * 8);
            *(uint4v*)(As + row * 40 + seg * 8) = va;
            uint4v vb = *(const uint4v*)(WbT + (size_t)(n0 + row) * 512 + k0 + seg * 8);
            *(uint4v*)(Bs + row * 40 + seg * 8) = vb;
        }
        __syncthreads();

        bf16x8 af[4], bfr[4];
#pragma unroll
        for (int tm = 0; tm < 4; tm++)
            af[tm] = *(const bf16x8*)(As + (mw + tm * 16 + lr) * 40 + lq * 8);
#pragma unroll
        for (int tn = 0; tn < 4; tn++)
            bfr[tn] = *(const bf16x8*)(Bs + (nw + tn * 16 + lr) * 40 + lq * 8);
#pragma unroll
        for (int tm = 0; tm < 4; tm++)
#pragma unroll
            for (int tn = 0; tn < 4; tn++)
                acc[tm][tn] = MFMA16(af[tm], bfr[tn], acc[tm][tn]);
        __syncthreads();
    }

#pragma unroll
    for (int tm = 0; tm < 4; tm++)
#pragma unroll
        for (int tn = 0; tn < 4; tn++)
#pragma unroll
            for (int r = 0; r < 4; r++) {
                int row = m0 + mw + tm * 16 + lq * 4 + r;
                int col = n0 + nw + tn * 16 + lr;
                gxOut[(size_t)row * 4096 + col] = f2bf(acc[tm][tn][r]);
            }
}

// ---------------------------------------------------------------------------
// Kernel 2: persistent scan (R5 structure). 64 WGs x 512 threads.
//   R9 knob: barriers B/D are raw s_barrier + explicit compiler fences.
//   B: lgkmcnt(0) (own ds_writes complete) — NO vmcnt drain.
//   D: no waitcnt — every wave's out-store consumed its ds_reads, so reads
//      are complete before arrival; h/out stores drain in background and are
//      absorbed by the next sweep's vmcnt(0).
// ---------------------------------------------------------------------------
#define NWG_SCAN 64
#define LDS2_BYTES 82432
#define KSTR 2560
#define CSTR 20

__device__ __forceinline__ void fence_barrier_lgkm() {
    asm volatile("s_waitcnt lgkmcnt(0)" ::: "memory");
    __builtin_amdgcn_sched_barrier(0);
    __builtin_amdgcn_s_barrier();
    __builtin_amdgcn_sched_barrier(0);
    asm volatile("" ::: "memory");
}
__device__ __forceinline__ void fence_barrier_plain() {
    asm volatile("" ::: "memory");
    __builtin_amdgcn_sched_barrier(0);
    __builtin_amdgcn_s_barrier();
    __builtin_amdgcn_sched_barrier(0);
    asm volatile("" ::: "memory");
}

__global__ void __launch_bounds__(512, 1) lstm_scan(
    const float* __restrict__ Whf, const float* __restrict__ Whi,
    const float* __restrict__ Who, const float* __restrict__ Whc,
    const float* __restrict__ Bf,  const float* __restrict__ Bi,
    const float* __restrict__ Bo,  const float* __restrict__ Bc,
    const unsigned short* __restrict__ gx,
    unsigned short* __restrict__ hhist,   // [512][32][1024] bf16, prefilled 0xFF
    float* __restrict__ out)
{
    extern __shared__ char lds[];
    float* glds = (float*)lds;            // 81920 B
    float* blds = (float*)(lds + 81920);  //   512 B

    const int tid  = threadIdx.x;
    const int w    = blockIdx.x;
    const int bg   = w & 1;
    const int cg   = w >> 1;
    const int j0   = cg * 32;
    const int lane = tid & 63;
    const int kq   = tid >> 6;
    const int lr   = lane & 15;
    const int lq   = lane >> 4;

    if (tid < 128) {
        int g = tid >> 5, jj = tid & 31;
        const float* bp = (g == 0) ? Bf : (g == 1) ? Bi : (g == 2) ? Bo : Bc;
        blds[tid] = bp[j0 + jj];
    }

    bf16x8 bfrag[8][4];
#pragma unroll
    for (int ct = 0; ct < 8; ct++) {
        int c = ct * 16 + lr;
        int g = c >> 5, jj = c & 31;
        const float* wp = (g == 0) ? Whf : (g == 1) ? Whi : (g == 2) ? Who : Whc;
#pragma unroll
        for (int ks = 0; ks < 4; ks++) {
            int kbase = kq * 128 + ks * 32 + lq * 8;
            bf16x8 b;
#pragma unroll
            for (int j = 0; j < 8; j++)
                b[j] = (short)f2bf(wp[(size_t)(kbase + j) * 1024 + j0 + jj]);
            bfrag[ct][ks] = b;
        }
    }

    const int cb = tid >> 5;
    const int cj = tid & 31;
    const int b  = bg * 16 + cb;
    float c_reg = 0.f;

    __syncthreads();

    for (int t = 0; t < 512; t++) {
        const unsigned short* gxr = gx + ((size_t)(b * 512 + t)) * 4096 + j0 + cj;
        float gxv[4];
#pragma unroll
        for (int g = 0; g < 4; g++) gxv[g] = bf2f(gxr[(size_t)g * 1024]);

        if (t > 0) {
            const unsigned short* hsrc = hhist + (size_t)t * 32768;

            f32x4 acc[8];
#pragma unroll
            for (int ct = 0; ct < 8; ct++) acc[ct] = (f32x4){0.f, 0.f, 0.f, 0.f};

            uint4v fa[4];
            unsigned int pend = 0xFu;
            while (pend) {
#pragma unroll
                for (int ks = 0; ks < 4; ks++) {
                    if (pend & (1u << ks)) {
                        const unsigned short* p = hsrc + (bg * 16 + lr) * 1024
                                                   + kq * 128 + ks * 32 + lq * 8;
                        asm volatile("global_load_dwordx4 %0, %1, off sc0 sc1"
                                     : "=v"(fa[ks]) : "v"(p));
                    }
                }
                asm volatile("s_waitcnt vmcnt(0)" ::: "memory");
                __builtin_amdgcn_sched_barrier(0);

                unsigned int np = 0;
#pragma unroll
                for (int ks = 0; ks < 4; ks++) {
                    if (pend & (1u << ks)) {
                        uint4v u = fa[ks];
                        bool dirty = (u[0] == 0xFFFFFFFFu) | (u[1] == 0xFFFFFFFFu)
                                   | (u[2] == 0xFFFFFFFFu) | (u[3] == 0xFFFFFFFFu);
                        if (__any(dirty)) {
                            np |= 1u << ks;
                        } else {
                            bf16x8 a = __builtin_bit_cast(bf16x8, u);
#pragma unroll
                            for (int ct = 0; ct < 8; ct++)
                                acc[ct] = MFMA16(a, bfrag[ct][ks], acc[ct]);
                        }
                    }
                }
                pend = np;
            }

#pragma unroll
            for (int ct = 0; ct < 8; ct++)
                *(f32x4*)(glds + kq * KSTR + (ct * 16 + lr) * CSTR + lq * 4)
                    = acc[ct];
        }
        // barrier B: own ds_writes complete; NO vmem drain
        fence_barrier_lgkm();

        float sg[4];
#pragma unroll
        for (int g = 0; g < 4; g++) {
            float dot = 0.f;
            if (t > 0) {
#pragma unroll
                for (int p = 0; p < 8; p++)
                    dot += glds[p * KSTR + (g * 32 + cj) * CSTR + cb];
            }
            sg[g] = sigmoidf_(dot + gxv[g] + blds[g * 32 + cj]);
        }
        float cn = sg[0] * c_reg + sg[1] * sg[3];
        c_reg = cn;
        float hn = sg[2] * tanhf_(cn);

        if (t < 511) {
            unsigned int hb = (unsigned int)f2bf(hn);
            unsigned int nb = (unsigned int)__shfl_xor((int)hb, 1);
            unsigned int v  = (hb & 0xFFFFu) | (nb << 16);
            unsigned int v2 = (unsigned int)__shfl_xor((int)v, 2);
            unsigned int v4 = (unsigned int)__shfl_xor((int)v, 4);
            unsigned int v6 = (unsigned int)__shfl_xor((int)v2, 4);
            if ((cj & 7) == 0) {
                uint4v q;
                q[0] = v; q[1] = v2; q[2] = v4; q[3] = v6;
                unsigned short* dst = hhist + (size_t)(t + 1) * 32768
                                      + b * 1024 + j0 + cj;
                asm volatile("global_store_dwordx4 %0, %1, off sc1"
                             :: "v"(dst), "v"(q) : "memory");
            }
            out[((size_t)b * 512 + t) * 1024 + j0 + cj] = sg[2];
        } else {
            out[((size_t)b * 512 + t) * 1024 + j0 + cj] = sg[2];
            out[16777216 + b * 1024 + j0 + cj]          = hn;   // ht
            out[16777216 + 32768 + b * 1024 + j0 + cj]  = cn;   // ct
        }
        // barrier D: ds_reads already consumed (out-store data dep);
        // h/out stores intentionally left in flight.
        fence_barrier_plain();
    }
}

__global__ void ws_diag(float* out, float mb) { out[threadIdx.x] = -mb; }

extern "C" void kernel_launch(void* const* d_in, const int* in_sizes, int n_in,
                              void* d_out, int out_size, void* d_ws, size_t ws_size,
                              hipStream_t stream)
{
    const float* x   = (const float*)d_in[0];
    const float* wxf = (const float*)d_in[1];
    const float* whf = (const float*)d_in[2];
    const float* bhf = (const float*)d_in[3];
    const float* wxi = (const float*)d_in[4];
    const float* whi = (const float*)d_in[5];
    const float* bhi = (const float*)d_in[6];
    const float* wxo = (const float*)d_in[7];
    const float* who = (const float*)d_in[8];
    const float* bho = (const float*)d_in[9];
    const float* wxc = (const float*)d_in[10];
    const float* whc = (const float*)d_in[11];
    const float* bhc = (const float*)d_in[12];
    float* out = (float*)d_out;

    const size_t GX_BYTES = (size_t)16384 * 4096 * 2;    // 134217728
    const size_t HH_BYTES = (size_t)512 * 32 * 1024 * 2; //  33554432
    const size_t NEED = GX_BYTES + HH_BYTES;

    if (ws_size < NEED) {
        ws_diag<<<dim3(1), dim3(256), 0, stream>>>(out, (float)(ws_size >> 20));
        return;
    }

    unsigned short* gxbuf = (unsigned short*)d_ws;
    unsigned short* hh    = (unsigned short*)((char*)d_ws + GX_BYTES);
    unsigned short* Xb  = hh;
    unsigned short* WbT = hh + 8388608;   // +16MB

    (void)hipFuncSetAttribute((const void*)lstm_scan,
                              hipFuncAttributeMaxDynamicSharedMemorySize, LDS2_BYTES);

    prep<<<dim3(4608), dim3(256), 0, stream>>>(x, wxf, wxi, wxo, wxc, Xb, WbT);
    gx_gemm2<<<dim3(128, 32), dim3(256), 0, stream>>>(Xb, WbT, gxbuf);
    hipMemsetAsync(hh, 0xFF, HH_BYTES, stream);
    lstm_scan<<<dim3(NWG_SCAN), dim3(512), LDS2_BYTES, stream>>>(
        whf, whi, who, whc, bhf, bhi, bho, bhc, gxbuf, hh, out);
}